// Round 4
// baseline (374.003 us; speedup 1.0000x reference)
//
#include <hip/hip_runtime.h>
#include <math.h>

#define N_PTS   10000
#define CIN     64
#define COUT    32
#define KCAP    32
#define RADIUSF 0.07f
#define NCELLS  27
#define QB      4      // queries per block (4 waves, wave w owns query w)
#define MAXC    64     // per-query in-radius list cap (Poisson(14.4): P(>64) ~ 1e-26)

// ---- setup kernel: Wt[cell][o][f] = W[cell][f][o] (makes phase-3 reads float4-able)
__global__ void transpose_W_kernel(const float* __restrict__ W, float* __restrict__ Wt) {
    int idx = blockIdx.x * 256 + threadIdx.x;
    if (idx >= NCELLS * CIN * COUT) return;
    int o    = idx & (COUT - 1);
    int f    = (idx / COUT) & (CIN - 1);
    int cell = idx / (COUT * CIN);
    Wt[(cell * COUT + o) * CIN + f] = W[idx];
}

template <bool USE_WT>
__global__ __launch_bounds__(256) void cconv_batched_kernel(
    const float* __restrict__ feats,
    const float* __restrict__ points,
    const float* __restrict__ Wt,      // transposed (if USE_WT)
    const float* __restrict__ W,       // original layout (fallback)
    const float* __restrict__ bias,
    float* __restrict__ out)
{
    const int qbase = blockIdx.x * QB;
    const int tid   = threadIdx.x;
    const int lane  = tid & 63;
    const int wave  = tid >> 6;

    __shared__ __align__(16) float sA[QB][NCELLS][CIN];  // 27648 B fp32 accumulators
    __shared__ float s_d2[QB][MAXC];
    __shared__ int   s_idx[QB][MAXC];
    __shared__ int   s_sel[QB][KCAP];
    __shared__ int   s_cnt[QB];
    __shared__ float sQ[QB][4];                          // x,y,z,|q|^2

    // ---- init ----
    if (tid < QB) {
        s_cnt[tid] = 0;
        int qi = qbase + tid;
        float qx = points[3 * qi + 0];
        float qy = points[3 * qi + 1];
        float qz = points[3 * qi + 2];
        sQ[tid][0] = qx; sQ[tid][1] = qy; sQ[tid][2] = qz;
        sQ[tid][3] = qx * qx + qy * qy + qz * qz;        // same expr as ref's sq
    }
    for (int i = tid; i < QB * NCELLS * CIN; i += 256) ((float*)sA)[i] = 0.0f;
    __syncthreads();

    // ---- Phase 1: N^2 radius scan, 4 queries share each loaded point ----
    float q_x[QB], q_y[QB], q_z[QB], q_s[QB];
    #pragma unroll
    for (int q = 0; q < QB; ++q) {
        q_x[q] = sQ[q][0]; q_y[q] = sQ[q][1]; q_z[q] = sQ[q][2]; q_s[q] = sQ[q][3];
    }
    const float r2 = RADIUSF * RADIUSF;

    for (int j = tid; j < N_PTS; j += 256) {
        float x = points[3 * j + 0];
        float y = points[3 * j + 1];
        float z = points[3 * j + 2];
        float sqj = x * x + y * y + z * z;
        #pragma unroll
        for (int q = 0; q < QB; ++q) {
            float dot = q_x[q] * x + q_y[q] * y + q_z[q] * z;
            float d2 = (q_s[q] + sqj) - 2.0f * dot;      // identical form to ref/Round-3
            if (d2 <= r2) {
                int pos = atomicAdd(&s_cnt[q], 1);
                if (pos < MAXC) { s_d2[q][pos] = d2; s_idx[q][pos] = j; }
            }
        }
    }
    __syncthreads();

    // ---- from here on, wave w owns query w exclusively (no more block syncs) ----
    const int q = wave;
    int M = s_cnt[q]; if (M > MAXC) M = MAXC;
    const int cnt = (M > KCAP) ? KCAP : M;

    // exact top-32 selection when over-full (tie-break matches lax.top_k: d2, then index)
    if (M > KCAP) {
        if (lane < M) {
            float dc = s_d2[q][lane];
            int   ic = s_idx[q][lane];
            int rank = 0;
            for (int m = 0; m < M; ++m) {
                float dm = s_d2[q][m];
                int   im = s_idx[q][m];
                rank += (dm < dc || (dm == dc && im < ic)) ? 1 : 0;
            }
            if (rank < KCAP) s_sel[q][rank] = s_idx[q][lane];
        }
        // wave-local: s_sel[q] written and read by the same wave; lockstep => no barrier needed
    }
    const int* nbr = (M > KCAP) ? s_sel[q] : s_idx[q];

    // ---- Phase 2: trilinear scatter-accumulate into sA[q] (lane = feature) ----
    const float qx = q_x[q], qy = q_y[q], qz = q_z[q];
    for (int k = 0; k < cnt; ++k) {
        int j = nbr[k];
        float x = points[3 * j + 0];
        float y = points[3 * j + 1];
        float z = points[3 * j + 2];
        float rx = (x - qx) / RADIUSF;
        float ry = (y - qy) / RADIUSF;
        float rz = (z - qz) / RADIUSF;
        float l2 = sqrtf(rx * rx + ry * ry + rz * rz);
        float ax = fabsf(rx), ay = fabsf(ry), az = fabsf(rz);
        float linf = fmaxf(fmaxf(ax, ay), az);
        float s = (linf > 0.0f) ? (l2 / fmaxf(linf, 1e-12f)) : 0.0f;
        float tx = rx * s, ty = ry * s, tz = rz * s;
        float cx = (tx + 1.0f) * 0.5f * 2.0f;
        float cy = (ty + 1.0f) * 0.5f * 2.0f;
        float cz = (tz + 1.0f) * 0.5f * 2.0f;
        float c0x = fminf(fmaxf(floorf(cx), 0.0f), 1.0f);
        float c0y = fminf(fmaxf(floorf(cy), 0.0f), 1.0f);
        float c0z = fminf(fmaxf(floorf(cz), 0.0f), 1.0f);
        float fx = cx - c0x;
        float fy = cy - c0y;
        float fz = cz - c0z;
        int i0 = (int)c0x, i1 = (int)c0y, i2 = (int)c0z;
        int base = i0 * 9 + i1 * 3 + i2;

        float gx0 = 1.0f - fx, gx1 = fx;
        float gy0 = 1.0f - fy, gy1 = fy;
        float gz0 = 1.0f - fz, gz1 = fz;

        float featv = feats[j * CIN + lane];

        sA[q][base + 0 ][lane] += (gx0 * gy0) * gz0 * featv;
        sA[q][base + 1 ][lane] += (gx0 * gy0) * gz1 * featv;
        sA[q][base + 3 ][lane] += (gx0 * gy1) * gz0 * featv;
        sA[q][base + 4 ][lane] += (gx0 * gy1) * gz1 * featv;
        sA[q][base + 9 ][lane] += (gx1 * gy0) * gz0 * featv;
        sA[q][base + 10][lane] += (gx1 * gy0) * gz1 * featv;
        sA[q][base + 12][lane] += (gx1 * gy1) * gz0 * featv;
        sA[q][base + 13][lane] += (gx1 * gy1) * gz1 * featv;
    }
    // wave-local: sA[q] written and read by this wave only; lockstep => no barrier needed

    // ---- Phase 3: out[q][o] = sum_{cell,f} sA[q][cell][f] * W[cell][f][o] ----
    const int o    = lane & 31;
    const int half = lane >> 5;
    const int c_begin = half ? 14 : 0;
    const int c_end   = half ? 27 : 14;
    float acc;

    if (USE_WT) {
        float4 acc4 = make_float4(0.f, 0.f, 0.f, 0.f);
        for (int cell = c_begin; cell < c_end; ++cell) {
            const float4* __restrict__ wrow = (const float4*)(Wt + (cell * COUT + o) * CIN);
            const float4* __restrict__ arow = (const float4*)(&sA[q][cell][0]);
            #pragma unroll
            for (int f4 = 0; f4 < CIN / 4; ++f4) {
                float4 w4 = wrow[f4];          // contiguous per lane (L1/L2-resident)
                float4 a4 = arow[f4];          // ds_read_b128, uniform per half => broadcast
                acc4.x = fmaf(a4.x, w4.x, acc4.x);
                acc4.y = fmaf(a4.y, w4.y, acc4.y);
                acc4.z = fmaf(a4.z, w4.z, acc4.z);
                acc4.w = fmaf(a4.w, w4.w, acc4.w);
            }
        }
        acc = (acc4.x + acc4.y) + (acc4.z + acc4.w);
    } else {
        acc = 0.0f;
        for (int cell = c_begin; cell < c_end; ++cell) {
            const float* __restrict__ Wrow = W + (cell * CIN) * COUT + o;
            #pragma unroll 8
            for (int f = 0; f < CIN; ++f) {
                acc += sA[q][cell][f] * Wrow[f * COUT];
            }
        }
    }
    acc += __shfl_xor(acc, 32);

    if (lane < COUT) {
        float nn = (float)cnt;
        out[(qbase + q) * COUT + lane] = acc / fmaxf(nn, 1.0f) + bias[lane];
    }
}

extern "C" void kernel_launch(void* const* d_in, const int* in_sizes, int n_in,
                              void* d_out, int out_size, void* d_ws, size_t ws_size,
                              hipStream_t stream) {
    const float* feats  = (const float*)d_in[0];
    const float* points = (const float*)d_in[1];
    const float* W      = (const float*)d_in[2];
    const float* bias   = (const float*)d_in[3];
    float* out = (float*)d_out;

    const size_t wt_bytes = (size_t)NCELLS * CIN * COUT * sizeof(float);
    const int nblk = N_PTS / QB;   // 2500

    if (ws_size >= wt_bytes) {
        float* Wt = (float*)d_ws;
        transpose_W_kernel<<<(NCELLS * CIN * COUT + 255) / 256, 256, 0, stream>>>(W, Wt);
        cconv_batched_kernel<true><<<nblk, 256, 0, stream>>>(feats, points, Wt, W, bias, out);
    } else {
        cconv_batched_kernel<false><<<nblk, 256, 0, stream>>>(feats, points, nullptr, W, bias, out);
    }
}

// Round 5
// 164.722 us; speedup vs baseline: 2.2705x; 2.2705x over previous
//
#include <hip/hip_runtime.h>
#include <math.h>

#define N_PTS   10000
#define CIN     64
#define COUT    32
#define KCAP    32
#define RADIUSF 0.07f
#define NCELLS  27
#define QB      4      // queries per block (4 waves; wave w owns query w)
#define MAXC    64     // per-query in-radius cap (Poisson(14.4): P(>64) ~ 1e-26)
#define GRES    14     // hash grid resolution; 1/14 = 0.0714 > R = 0.07
#define GCELLS  (GRES * GRES * GRES)   // 2744

__device__ __forceinline__ void cell_coords(float x, float y, float z,
                                            int& cx, int& cy, int& cz) {
    cx = (int)(x * (float)GRES); if (cx > GRES - 1) cx = GRES - 1; if (cx < 0) cx = 0;
    cy = (int)(y * (float)GRES); if (cy > GRES - 1) cy = GRES - 1; if (cy < 0) cy = 0;
    cz = (int)(z * (float)GRES); if (cz > GRES - 1) cz = GRES - 1; if (cz < 0) cz = 0;
}

// ---- grid build ----
__global__ void grid_count_kernel(const float* __restrict__ pts, int* __restrict__ counts) {
    int i = blockIdx.x * 256 + threadIdx.x;
    if (i >= N_PTS) return;
    int cx, cy, cz;
    cell_coords(pts[3 * i], pts[3 * i + 1], pts[3 * i + 2], cx, cy, cz);
    atomicAdd(&counts[(cx * GRES + cy) * GRES + cz], 1);
}

__global__ __launch_bounds__(1024) void grid_scan_kernel(const int* __restrict__ counts,
                                                         int* __restrict__ offsets,
                                                         int* __restrict__ cursor) {
    __shared__ int s[1024];
    const int t = threadIdx.x;
    const int c0 = t * 3;
    int v0 = 0, v1 = 0, v2 = 0, sum = 0;
    if (c0 + 0 < GCELLS) { v0 = counts[c0 + 0]; sum += v0; }
    if (c0 + 1 < GCELLS) { v1 = counts[c0 + 1]; sum += v1; }
    if (c0 + 2 < GCELLS) { v2 = counts[c0 + 2]; sum += v2; }
    s[t] = sum;
    __syncthreads();
    for (int d = 1; d < 1024; d <<= 1) {           // inclusive Hillis-Steele
        int add = (t >= d) ? s[t - d] : 0;
        __syncthreads();
        s[t] += add;
        __syncthreads();
    }
    int base = (t == 0) ? 0 : s[t - 1];
    if (c0 + 0 < GCELLS) { offsets[c0 + 0] = base; cursor[c0 + 0] = base; base += v0; }
    if (c0 + 1 < GCELLS) { offsets[c0 + 1] = base; cursor[c0 + 1] = base; base += v1; }
    if (c0 + 2 < GCELLS) { offsets[c0 + 2] = base; cursor[c0 + 2] = base; base += v2; }
    if (t == 1023) offsets[GCELLS] = s[1023];
}

__global__ void grid_scatter_kernel(const float* __restrict__ pts,
                                    int* __restrict__ cursor, int* __restrict__ sorted) {
    int i = blockIdx.x * 256 + threadIdx.x;
    if (i >= N_PTS) return;
    int cx, cy, cz;
    cell_coords(pts[3 * i], pts[3 * i + 1], pts[3 * i + 2], cx, cy, cz);
    int pos = atomicAdd(&cursor[(cx * GRES + cy) * GRES + cz], 1);
    sorted[pos] = i;
}

// ---- main fused kernel: grid-accelerated radius search + cconv ----
__global__ __launch_bounds__(256) void cconv_grid_kernel(
    const float* __restrict__ feats,
    const float* __restrict__ points,
    const float* __restrict__ W,
    const float* __restrict__ bias,
    const int*   __restrict__ offsets,
    const int*   __restrict__ sorted,
    float* __restrict__ out)
{
    const int tid  = threadIdx.x;
    const int lane = tid & 63;
    const int wave = tid >> 6;

    __shared__ __align__(16) float sA[QB][NCELLS][CIN];   // per-wave accumulators
    __shared__ float s_d2[QB][MAXC];
    __shared__ int   s_idx[QB][MAXC];
    __shared__ int   s_sel[QB][KCAP];
    __shared__ int   s_cnt[QB];

    // per-wave init (no cross-wave deps -> no barriers anywhere in this kernel)
    if (lane == 0) s_cnt[wave] = 0;
    for (int i = lane; i < NCELLS * CIN; i += 64) ((float*)sA[wave])[i] = 0.0f;

    const int q_flat = blockIdx.x * QB + wave;
    const int qi = sorted[q_flat];                 // cell-sorted order: spatial locality
    const float qx = points[3 * qi + 0];
    const float qy = points[3 * qi + 1];
    const float qz = points[3 * qi + 2];
    const float sqn = qx * qx + qy * qy + qz * qz; // same expr as ref's sq
    const float r2 = RADIUSF * RADIUSF;

    int cx, cy, cz;
    cell_coords(qx, qy, qz, cx, cy, cz);

    // ---- Phase 1: candidate scan over 27 neighbor cells (9 contiguous z-rows) ----
    for (int dx = -1; dx <= 1; ++dx) {
        int cxx = cx + dx;
        if (cxx < 0 || cxx > GRES - 1) continue;
        for (int dy = -1; dy <= 1; ++dy) {
            int cyy = cy + dy;
            if (cyy < 0 || cyy > GRES - 1) continue;
            int zlo = cz - 1; if (zlo < 0) zlo = 0;
            int zhi = cz + 1; if (zhi > GRES - 1) zhi = GRES - 1;
            int row = (cxx * GRES + cyy) * GRES;
            int s = offsets[row + zlo];
            int e = offsets[row + zhi + 1];
            for (int base = s; base < e; base += 64) {
                int t = base + lane;
                if (t < e) {
                    int j = sorted[t];
                    float x = points[3 * j + 0];
                    float y = points[3 * j + 1];
                    float z = points[3 * j + 2];
                    float sqj = x * x + y * y + z * z;
                    float dot = qx * x + qy * y + qz * z;
                    float d2 = (sqn + sqj) - 2.0f * dot;   // byte-identical to ref form
                    if (d2 <= r2) {
                        int pos = atomicAdd(&s_cnt[wave], 1);
                        if (pos < MAXC) { s_d2[wave][pos] = d2; s_idx[wave][pos] = j; }
                    }
                }
            }
        }
    }

    int M = s_cnt[wave]; if (M > MAXC) M = MAXC;
    const int cnt = (M > KCAP) ? KCAP : M;

    // exact top-32 when over-full (tie-break matches lax.top_k: d2, then index)
    if (M > KCAP) {
        if (lane < M) {
            float dc = s_d2[wave][lane];
            int   ic = s_idx[wave][lane];
            int rank = 0;
            for (int m = 0; m < M; ++m) {
                float dm = s_d2[wave][m];
                int   im = s_idx[wave][m];
                rank += (dm < dc || (dm == dc && im < ic)) ? 1 : 0;
            }
            if (rank < KCAP) s_sel[wave][rank] = s_idx[wave][lane];
        }
    }
    const int* nbr = (M > KCAP) ? s_sel[wave] : s_idx[wave];

    // ---- Phase 2: trilinear scatter-accumulate (lane = feature) ----
    for (int k = 0; k < cnt; ++k) {
        int j = nbr[k];
        float x = points[3 * j + 0];
        float y = points[3 * j + 1];
        float z = points[3 * j + 2];
        float rx = (x - qx) / RADIUSF;
        float ry = (y - qy) / RADIUSF;
        float rz = (z - qz) / RADIUSF;
        float l2 = sqrtf(rx * rx + ry * ry + rz * rz);
        float ax = fabsf(rx), ay = fabsf(ry), az = fabsf(rz);
        float linf = fmaxf(fmaxf(ax, ay), az);
        float s = (linf > 0.0f) ? (l2 / fmaxf(linf, 1e-12f)) : 0.0f;
        float tx = rx * s, ty = ry * s, tz = rz * s;
        float cxf = (tx + 1.0f) * 0.5f * 2.0f;
        float cyf = (ty + 1.0f) * 0.5f * 2.0f;
        float czf = (tz + 1.0f) * 0.5f * 2.0f;
        float c0x = fminf(fmaxf(floorf(cxf), 0.0f), 1.0f);
        float c0y = fminf(fmaxf(floorf(cyf), 0.0f), 1.0f);
        float c0z = fminf(fmaxf(floorf(czf), 0.0f), 1.0f);
        float fx = cxf - c0x;
        float fy = cyf - c0y;
        float fz = czf - c0z;
        int i0 = (int)c0x, i1 = (int)c0y, i2 = (int)c0z;
        int base = i0 * 9 + i1 * 3 + i2;

        float gx0 = 1.0f - fx, gx1 = fx;
        float gy0 = 1.0f - fy, gy1 = fy;
        float gz0 = 1.0f - fz, gz1 = fz;

        float featv = feats[j * CIN + lane];

        sA[wave][base + 0 ][lane] += (gx0 * gy0) * gz0 * featv;
        sA[wave][base + 1 ][lane] += (gx0 * gy0) * gz1 * featv;
        sA[wave][base + 3 ][lane] += (gx0 * gy1) * gz0 * featv;
        sA[wave][base + 4 ][lane] += (gx0 * gy1) * gz1 * featv;
        sA[wave][base + 9 ][lane] += (gx1 * gy0) * gz0 * featv;
        sA[wave][base + 10][lane] += (gx1 * gy0) * gz1 * featv;
        sA[wave][base + 12][lane] += (gx1 * gy1) * gz0 * featv;
        sA[wave][base + 13][lane] += (gx1 * gy1) * gz1 * featv;
    }

    // ---- Phase 3: coalesced W reads (lane=o, consecutive), 4 independent fma chains ----
    const int o    = lane & 31;
    const int half = lane >> 5;
    const int c_begin = half ? 14 : 0;
    const int c_end   = half ? 27 : 14;
    float a0 = 0.f, a1 = 0.f, a2 = 0.f, a3 = 0.f;
    for (int cell = c_begin; cell < c_end; ++cell) {
        const float* __restrict__ Wrow = W + cell * (CIN * COUT) + o;
        const float* __restrict__ Arow = &sA[wave][cell][0];
        #pragma unroll
        for (int f = 0; f < CIN; f += 4) {
            a0 = fmaf(Arow[f + 0], Wrow[(f + 0) * COUT], a0);
            a1 = fmaf(Arow[f + 1], Wrow[(f + 1) * COUT], a1);
            a2 = fmaf(Arow[f + 2], Wrow[(f + 2) * COUT], a2);
            a3 = fmaf(Arow[f + 3], Wrow[(f + 3) * COUT], a3);
        }
    }
    float acc = (a0 + a1) + (a2 + a3);
    acc += __shfl_xor(acc, 32);

    if (lane < COUT) {
        float nn = (float)cnt;
        out[qi * COUT + lane] = acc / fmaxf(nn, 1.0f) + bias[lane];
    }
}

// ---- fallback (validated Round-3 kernel) if workspace is too small ----
__global__ __launch_bounds__(64) void cconv_fused_kernel(
    const float* __restrict__ feats,
    const float* __restrict__ points,
    const float* __restrict__ W,
    const float* __restrict__ bias,
    float* __restrict__ out)
{
    const int n    = blockIdx.x;
    const int lane = threadIdx.x;

    __shared__ float sA[NCELLS][CIN];
    __shared__ float s_d2[128];
    __shared__ int   s_idx[128];
    __shared__ int   s_rank[128];
    __shared__ int   s_sel[KCAP];
    __shared__ int   s_cnt;

    if (lane == 0) s_cnt = 0;
    for (int c = lane; c < NCELLS * CIN; c += 64) ((float*)sA)[c] = 0.0f;
    __syncthreads();

    const float qx = points[3 * n + 0];
    const float qy = points[3 * n + 1];
    const float qz = points[3 * n + 2];
    const float sqn = qx * qx + qy * qy + qz * qz;
    const float r2 = RADIUSF * RADIUSF;

    for (int j = lane; j < N_PTS; j += 64) {
        float x = points[3 * j + 0];
        float y = points[3 * j + 1];
        float z = points[3 * j + 2];
        float sqj = x * x + y * y + z * z;
        float dot = qx * x + qy * y + qz * z;
        float d2 = (sqn + sqj) - 2.0f * dot;
        if (d2 <= r2) {
            int pos = atomicAdd(&s_cnt, 1);
            if (pos < 128) { s_d2[pos] = d2; s_idx[pos] = j; }
        }
    }
    __syncthreads();

    int M = s_cnt; if (M > 128) M = 128;
    int cnt;
    if (M > KCAP) {
        for (int c = lane; c < M; c += 64) {
            float dc = s_d2[c]; int ic = s_idx[c]; int rank = 0;
            for (int m = 0; m < M; ++m) {
                float dm = s_d2[m]; int im = s_idx[m];
                rank += (dm < dc || (dm == dc && im < ic)) ? 1 : 0;
            }
            s_rank[c] = rank;
        }
        __syncthreads();
        for (int c = lane; c < M; c += 64) {
            int r = s_rank[c];
            if (r < KCAP) s_sel[r] = s_idx[c];
        }
        __syncthreads();
        cnt = KCAP;
    } else cnt = M;
    const int* nbr = (M > KCAP) ? s_sel : s_idx;

    for (int k = 0; k < cnt; ++k) {
        int j = nbr[k];
        float x = points[3 * j + 0];
        float y = points[3 * j + 1];
        float z = points[3 * j + 2];
        float rx = (x - qx) / RADIUSF;
        float ry = (y - qy) / RADIUSF;
        float rz = (z - qz) / RADIUSF;
        float l2 = sqrtf(rx * rx + ry * ry + rz * rz);
        float ax = fabsf(rx), ay = fabsf(ry), az = fabsf(rz);
        float linf = fmaxf(fmaxf(ax, ay), az);
        float s = (linf > 0.0f) ? (l2 / fmaxf(linf, 1e-12f)) : 0.0f;
        float tx = rx * s, ty = ry * s, tz = rz * s;
        float cxf = (tx + 1.0f) * 0.5f * 2.0f;
        float cyf = (ty + 1.0f) * 0.5f * 2.0f;
        float czf = (tz + 1.0f) * 0.5f * 2.0f;
        float c0x = fminf(fmaxf(floorf(cxf), 0.0f), 1.0f);
        float c0y = fminf(fmaxf(floorf(cyf), 0.0f), 1.0f);
        float c0z = fminf(fmaxf(floorf(czf), 0.0f), 1.0f);
        float fx = cxf - c0x, fy = cyf - c0y, fz = czf - c0z;
        int i0 = (int)c0x, i1 = (int)c0y, i2 = (int)c0z;
        int base = i0 * 9 + i1 * 3 + i2;
        float gx0 = 1.0f - fx, gx1 = fx;
        float gy0 = 1.0f - fy, gy1 = fy;
        float gz0 = 1.0f - fz, gz1 = fz;
        float featv = feats[j * CIN + lane];
        sA[base + 0 ][lane] += (gx0 * gy0) * gz0 * featv;
        sA[base + 1 ][lane] += (gx0 * gy0) * gz1 * featv;
        sA[base + 3 ][lane] += (gx0 * gy1) * gz0 * featv;
        sA[base + 4 ][lane] += (gx0 * gy1) * gz1 * featv;
        sA[base + 9 ][lane] += (gx1 * gy0) * gz0 * featv;
        sA[base + 10][lane] += (gx1 * gy0) * gz1 * featv;
        sA[base + 12][lane] += (gx1 * gy1) * gz0 * featv;
        sA[base + 13][lane] += (gx1 * gy1) * gz1 * featv;
    }
    __syncthreads();

    const int o    = lane & 31;
    const int half = lane >> 5;
    const int c_begin = half ? 14 : 0;
    const int c_end   = half ? 27 : 14;
    float acc = 0.0f;
    for (int cell = c_begin; cell < c_end; ++cell) {
        const float* __restrict__ Wrow = W + (cell * CIN) * COUT + o;
        #pragma unroll 8
        for (int f = 0; f < CIN; ++f) acc += sA[cell][f] * Wrow[f * COUT];
    }
    acc += __shfl_xor(acc, 32);
    if (lane < COUT) {
        float nn = (float)cnt;
        out[n * COUT + lane] = acc / fmaxf(nn, 1.0f) + bias[lane];
    }
}

extern "C" void kernel_launch(void* const* d_in, const int* in_sizes, int n_in,
                              void* d_out, int out_size, void* d_ws, size_t ws_size,
                              hipStream_t stream) {
    const float* feats  = (const float*)d_in[0];
    const float* points = (const float*)d_in[1];
    const float* W      = (const float*)d_in[2];
    const float* bias   = (const float*)d_in[3];
    float* out = (float*)d_out;

    const size_t need = (size_t)(3 * GCELLS + 1 + N_PTS) * sizeof(int);  // ~73 KB

    if (ws_size >= need) {
        int* counts  = (int*)d_ws;              // GCELLS
        int* cursor  = counts + GCELLS;         // GCELLS
        int* offsets = cursor + GCELLS;         // GCELLS + 1
        int* sorted  = offsets + GCELLS + 1;    // N_PTS

        hipMemsetAsync(counts, 0, GCELLS * sizeof(int), stream);
        grid_count_kernel<<<(N_PTS + 255) / 256, 256, 0, stream>>>(points, counts);
        grid_scan_kernel<<<1, 1024, 0, stream>>>(counts, offsets, cursor);
        grid_scatter_kernel<<<(N_PTS + 255) / 256, 256, 0, stream>>>(points, cursor, sorted);
        cconv_grid_kernel<<<N_PTS / QB, QB * 64, 0, stream>>>(
            feats, points, W, bias, offsets, sorted, out);
    } else {
        cconv_fused_kernel<<<N_PTS, 64, 0, stream>>>(feats, points, W, bias, out);
    }
}